// Round 8
// baseline (232.051 us; speedup 1.0000x reference)
//
#include <hip/hip_runtime.h>
#include <hip/hip_bf16.h>
#include <stdint.h>

typedef __attribute__((ext_vector_type(8))) short bf16x8;
typedef __attribute__((ext_vector_type(4))) float f32x4;

#define AS1(p) ((const __attribute__((address_space(1))) uint32_t*)(p))
#define AS3(p) ((__attribute__((address_space(3))) uint32_t*)(p))

#define VMCNT12 asm volatile("s_waitcnt vmcnt(12)" ::: "memory")
#define VMCNT4  asm volatile("s_waitcnt vmcnt(4)" ::: "memory")
#define VMCNT0  asm volatile("s_waitcnt vmcnt(0)" ::: "memory")
#define LGKM0   asm volatile("s_waitcnt lgkmcnt(0)" ::: "memory")
#define SBAR    __builtin_amdgcn_s_barrier()
#define SCHED0  __builtin_amdgcn_sched_barrier(0)

__device__ __forceinline__ ushort f2bf(float f) {
  uint32_t u = __float_as_uint(f);
  uint32_t r = (u + 0x7fffu + ((u >> 16) & 1u)) >> 16;
  return (ushort)r;
}

// fp32x8 -> bf16x8 via packed cvt (RTNE)
__device__ __forceinline__ uint4 cvt8u(float4 a0, float4 a1) {
  uint4 r;
  asm("v_cvt_pk_bf16_f32 %0, %1, %2" : "=v"(r.x) : "v"(a0.x), "v"(a0.y));
  asm("v_cvt_pk_bf16_f32 %0, %1, %2" : "=v"(r.y) : "v"(a0.z), "v"(a0.w));
  asm("v_cvt_pk_bf16_f32 %0, %1, %2" : "=v"(r.z) : "v"(a1.x), "v"(a1.y));
  asm("v_cvt_pk_bf16_f32 %0, %1, %2" : "=v"(r.w) : "v"(a1.z), "v"(a1.w));
  return r;
}

// ---------------- pack: fp32 -> bf16 (weights only) ----------------
__global__ __launch_bounds__(256) void pack4(
    const float* __restrict__ s0, const float* __restrict__ s1,
    const float* __restrict__ s2, const float* __restrict__ s3,
    ushort* __restrict__ o0, ushort* __restrict__ o1,
    ushort* __restrict__ o2, ushort* __restrict__ o3, int n)
{
  const float* s; ushort* o;
  switch (blockIdx.y) {
    case 0: s = s0; o = o0; break;
    case 1: s = s1; o = o1; break;
    case 2: s = s2; o = o2; break;
    default: s = s3; o = o3; break;
  }
  int stride = gridDim.x * 1024;
  for (int i = (blockIdx.x * 256 + threadIdx.x) * 4; i < n; i += stride) {
    float4 v = *(const float4*)(s + i);
    ushort4 u;
    u.x = f2bf(v.x); u.y = f2bf(v.y); u.z = f2bf(v.z); u.w = f2bf(v.w);
    *(ushort4*)(o + i) = u;
  }
}

// ---------------- QKV projection GEMM, split-K, T4 counted-vmcnt pipeline ----------------
// Same data paths as r7 (verified conflict-free swizzles, LDS 48KB, fused fp32-A):
//   A: fp32 global -> regs (2 steps ahead, A/B named sets) -> cvt_pk -> swizzled At
//   B: bf16 weights via global_load_lds, pre-swizzled source, double-buffered Bt
// New sync structure: raw s_barrier (no vmcnt drain) + counted vmcnt(12) per iter
// so in-flight loads cross barriers; A-loads get ~2 iters of latency cover.
__global__ __launch_bounds__(256, 3) void gemm_qkv(
    const float* __restrict__ aq, const float* __restrict__ ak, const float* __restrict__ av,
    const ushort* __restrict__ wq, const ushort* __restrict__ wk, const ushort* __restrict__ wv,
    float* __restrict__ part, int lgs)
{
  __shared__ __align__(16) ushort At[128 * 64];        // 16KB bf16 (single buf)
  __shared__ __align__(16) ushort Bt[2][128 * 64];     // 2x16KB bf16
  int per = gridDim.x >> 3;
  int bid = blockIdx.x;
  int swz = (bid & 7) * per + (bid >> 3);
  int y = swz & 3, x = (swz >> 2) & 15, zz = swz >> 6;
  int g = zz >> lgs, s = zz & ((1 << lgs) - 1);
  const float* A; const ushort* Bm;
  if (g == 0)      { A = aq; Bm = wq; }
  else if (g == 1) { A = ak; Bm = wk; }
  else             { A = av; Bm = wv; }
  float* Pd = part + ((size_t)zz) * 1048576;   // plane 2048*512
  const int K = 4096;
  const int kchunk = K >> lgs;
  const int k0 = s * kchunk;
  const int nsteps = kchunk >> 6;              // 16 / 32 / 64 (even, >= 4)
  int rowBase = x * 128;
  int colBase = y * 128;
  int tid = threadIdx.x, l = tid & 63, w = tid >> 6;
  int wr = w >> 1, wc = w & 1, fr = l & 15, fq = l >> 4;

  // A staging map: thread t covers rows {j*32 + t>>3}, col-slot t&7 (32B fp32)
  int arow = tid >> 3;
  int aslot = tid & 7;
  const float* Abase = A + (size_t)(rowBase + arow) * K + aslot * 8;

  f32x4 acc[4][4];
#pragma unroll
  for (int m = 0; m < 4; ++m)
#pragma unroll
    for (int n = 0; n < 4; ++n) acc[m][n] = (f32x4){0.f, 0.f, 0.f, 0.f};

  float4 regA[4][2], regB[4][2];   // two named prefetch sets (static indexing only)

  auto loadTo = [&](float4 (&rg)[4][2], int step) {
    int ktn = k0 + step * 64;
#pragma unroll
    for (int j = 0; j < 4; ++j) {
      const float* p = Abase + (size_t)(j * 32) * K + ktn;
      rg[j][0] = *(const float4*)p;
      rg[j][1] = *(const float4*)(p + 4);
    }
  };
  auto cvtWrite = [&](float4 (&rg)[4][2]) {
#pragma unroll
    for (int j = 0; j < 4; ++j) {
      int row = j * 32 + arow;
      int sw = aslot ^ (row & 7);
      *(uint4*)((char*)At + row * 128 + sw * 16) = cvt8u(rg[j][0], rg[j][1]);
    }
  };
  auto stageB = [&](int bufIdx, int step) {
    int ktn = k0 + step * 64;
    char* Bbuf = (char*)Bt[bufIdx];
#pragma unroll
    for (int j = 0; j < 4; ++j) {
      int c = ((w * 4 + j) << 6) + l;
      int row = c >> 3, slot = c & 7;
      int srccol = (slot ^ (row & 7)) * 8;
      __builtin_amdgcn_global_load_lds(AS1(Bm + (size_t)(colBase + row) * K + ktn + srccol),
                                       AS3(Bbuf + c * 16), 16, 0, 0);
    }
  };
  auto mfmaPhase = [&](int bufIdx) {
    const char* Bbuf = (const char*)Bt[bufIdx];
#pragma unroll
    for (int kc = 0; kc < 2; ++kc) {
      bf16x8 af[4], bv[4];
#pragma unroll
      for (int m = 0; m < 4; ++m) {
        int r = wr * 64 + m * 16 + fr;
        int sl = (kc * 4 + fq) ^ (fr & 7);
        af[m] = *(const bf16x8*)((const char*)At + r * 128 + sl * 16);
      }
#pragma unroll
      for (int n = 0; n < 4; ++n) {
        int r = wc * 64 + n * 16 + fr;
        int sl = (kc * 4 + fq) ^ (fr & 7);
        bv[n] = *(const bf16x8*)(Bbuf + r * 128 + sl * 16);
      }
#pragma unroll
      for (int m = 0; m < 4; ++m)
#pragma unroll
        for (int n = 0; n < 4; ++n)
          acc[m][n] = __builtin_amdgcn_mfma_f32_16x16x32_bf16(af[m], bv[n], acc[m][n], 0, 0, 0);
    }
  };

  // ---- prologue: A(0)->regA, A(1)->regB, B(0)->Bt[0]; cvt A(0)->At ----
  loadTo(regA, 0);        // 8 vm
  loadTo(regB, 1);        // 8 vm
  stageB(0, 0);           // 4 vm   (20 outstanding)
  VMCNT12;                // retire loadA(0) -> regA ready
  SCHED0;
  cvtWrite(regA);         // At = A(0)
  LGKM0;
  // invariant entering iter 0: 12 outstanding = {loadA(1):8, stageB(0):4}

  // ---- main pairs: iters 0..nsteps-3 ----
  for (int it = 0; it < nsteps - 2; it += 2) {
    // even iter: load A(it+2)->regA, stage B(it+1)->Bt[1], mfma Bt[0], cvt regB
    loadTo(regA, it + 2);
    stageB(1, it + 1);
    VMCNT12;              // retire prev iter's 12: regB=A(it+1) ready, Bt[0] landed
    SBAR;                 // all waves synced: At(it), Bt[0] visible
    SCHED0;
    mfmaPhase(0);
    LGKM0;                // my ds_reads drained
    SBAR;                 // all At readers done -> safe to overwrite
    cvtWrite(regB);       // At = A(it+1)
    LGKM0;

    // odd iter: load A(it+3)->regB, stage B(it+2)->Bt[0], mfma Bt[1], cvt regA
    loadTo(regB, it + 3);
    stageB(0, it + 2);
    VMCNT12;
    SBAR;
    SCHED0;
    mfmaPhase(1);
    LGKM0;
    SBAR;
    cvtWrite(regA);       // At = A(it+2)
    LGKM0;
  }

  // ---- tail iter nsteps-2 (even parity): no A load, stage B(nsteps-1)->Bt[1] ----
  stageB(1, nsteps - 1);
  VMCNT4;                 // retire prev 12, keep this iter's 4
  SBAR;
  SCHED0;
  mfmaPhase(0);
  LGKM0;
  SBAR;
  cvtWrite(regB);         // At = A(nsteps-1)
  LGKM0;

  // ---- tail iter nsteps-1 (odd parity): nothing new in flight ----
  VMCNT0;
  SBAR;
  SCHED0;
  mfmaPhase(1);

#pragma unroll
  for (int m = 0; m < 4; ++m)
#pragma unroll
    for (int n = 0; n < 4; ++n)
#pragma unroll
      for (int r = 0; r < 4; ++r) {
        int row = rowBase + wr * 64 + m * 16 + fq * 4 + r;
        int col = colBase + wc * 64 + n * 16 + fr;
        Pd[(size_t)row * 512 + col] = acc[m][n][r];
      }
}

// ---------------- reduce split-K partials -> bf16 Q/K/V ----------------
__global__ __launch_bounds__(256) void reduce_qkv(
    const float* __restrict__ part, ushort* __restrict__ Qp, ushort* __restrict__ Kp,
    ushort* __restrict__ Vp, int lgs)
{
  int g = blockIdx.y;
  ushort* dst = g == 0 ? Qp : (g == 1 ? Kp : Vp);
  const float* p = part + (((size_t)g) << lgs) * 1048576;
  int i = (blockIdx.x * 256 + threadIdx.x) * 4;
  float4 acc = *(const float4*)(p + i);
  int splits = 1 << lgs;
  for (int s = 1; s < splits; ++s) {
    float4 b = *(const float4*)(p + (size_t)s * 1048576 + i);
    acc.x += b.x; acc.y += b.y; acc.z += b.z; acc.w += b.w;
  }
  ushort4 u;
  u.x = f2bf(acc.x); u.y = f2bf(acc.y); u.z = f2bf(acc.z); u.w = f2bf(acc.w);
  *(ushort4*)(dst + i) = u;
}

// ---------------- attention: per (b,h, row-half) block ----------------
__global__ __launch_bounds__(256) void attn(
    const ushort* __restrict__ Qp, const ushort* __restrict__ Kp, const ushort* __restrict__ Vp,
    float* __restrict__ Obuf, const float* __restrict__ temp)
{
  __shared__ __align__(16) ushort Qs[64 * 64];    // [crow][d]
  __shared__ __align__(16) ushort Ks[128 * 64];   // [e][d]
  __shared__ __align__(16) ushort Vt[64 * 128];   // [d][e] (transposed)
  __shared__ __align__(16) float  Sl[64 * 128];   // scores
  __shared__ __align__(16) ushort Pl[64 * 128];   // exp(S-max) bf16
  __shared__ float rsum[64];
  int bh = blockIdx.y, b = bh >> 3, h = bh & 7;
  int c0 = blockIdx.x * 64;
  int tid = threadIdx.x, l = tid & 63, w = tid >> 6;
  int wr = w >> 1, wc = w & 1, fr = l & 15, fq = l >> 4;
  float invT = 1.0f / temp[0];
  const size_t rowQ = (size_t)(b * 128 + c0);

  // stage Q (64 rows x 64 d)
#pragma unroll
  for (int j = 0; j < 2; ++j) {
    int c = ((w * 2 + j) << 6) + l, row = c >> 3, cc = c & 7;
    __builtin_amdgcn_global_load_lds(AS1(Qp + (rowQ + row) * 512 + h * 64 + cc * 8),
                                     AS3((char*)Qs + (w * 2 + j) * 1024), 16, 0, 0);
  }
  // stage K (128 rows x 64 d)
#pragma unroll
  for (int j = 0; j < 4; ++j) {
    int c = ((w * 4 + j) << 6) + l, row = c >> 3, cc = c & 7;
    __builtin_amdgcn_global_load_lds(AS1(Kp + (size_t)(b * 128 + row) * 512 + h * 64 + cc * 8),
                                     AS3((char*)Ks + (w * 4 + j) * 1024), 16, 0, 0);
  }
  // stage V transposed: Vt[d][e]
#pragma unroll
  for (int t = 0; t < 4; ++t) {
    int ch = tid + t * 256, e = ch >> 3, d0 = (ch & 7) * 8;
    bf16x8 vv = *(const bf16x8*)(Vp + (size_t)(b * 128 + e) * 512 + h * 64 + d0);
#pragma unroll
    for (int j = 0; j < 8; ++j) Vt[(d0 + j) * 128 + e] = (ushort)vv[j];
  }
  __syncthreads();

  // S = Q*K^T (64x128)
  f32x4 sa[2][4];
#pragma unroll
  for (int m = 0; m < 2; ++m)
#pragma unroll
    for (int n = 0; n < 4; ++n) sa[m][n] = (f32x4){0.f, 0.f, 0.f, 0.f};
#pragma unroll
  for (int kc = 0; kc < 2; ++kc) {
    bf16x8 aQ[2], bK[4];
#pragma unroll
    for (int m = 0; m < 2; ++m)
      aQ[m] = *(const bf16x8*)&Qs[(wr * 32 + m * 16 + fr) * 64 + kc * 32 + fq * 8];
#pragma unroll
    for (int n = 0; n < 4; ++n)
      bK[n] = *(const bf16x8*)&Ks[(wc * 64 + n * 16 + fr) * 64 + kc * 32 + fq * 8];
#pragma unroll
    for (int m = 0; m < 2; ++m)
#pragma unroll
      for (int n = 0; n < 4; ++n)
        sa[m][n] = __builtin_amdgcn_mfma_f32_16x16x32_bf16(aQ[m], bK[n], sa[m][n], 0, 0, 0);
  }
#pragma unroll
  for (int m = 0; m < 2; ++m)
#pragma unroll
    for (int n = 0; n < 4; ++n)
#pragma unroll
      for (int r = 0; r < 4; ++r)
        Sl[(wr * 32 + m * 16 + fq * 4 + r) * 128 + wc * 64 + n * 16 + fr] = sa[m][n][r] * invT;
  __syncthreads();

  // softmax: 4 threads per row, 32 cols each
  {
    int row = tid >> 2, qq = tid & 3;
    const float* srow = Sl + row * 128 + qq * 32;
    float4 va[8];
#pragma unroll
    for (int i = 0; i < 8; ++i) va[i] = *(const float4*)(srow + i * 4);
    float mx = -1e30f;
#pragma unroll
    for (int i = 0; i < 8; ++i)
      mx = fmaxf(mx, fmaxf(fmaxf(va[i].x, va[i].y), fmaxf(va[i].z, va[i].w)));
    mx = fmaxf(mx, __shfl_xor(mx, 1));
    mx = fmaxf(mx, __shfl_xor(mx, 2));
    float ssum = 0.f;
    ushort* prow = Pl + row * 128 + qq * 32;
#pragma unroll
    for (int i = 0; i < 8; ++i) {
      float e0 = __expf(va[i].x - mx), e1 = __expf(va[i].y - mx);
      float e2 = __expf(va[i].z - mx), e3 = __expf(va[i].w - mx);
      ssum += (e0 + e1) + (e2 + e3);
      ushort4 u; u.x = f2bf(e0); u.y = f2bf(e1); u.z = f2bf(e2); u.w = f2bf(e3);
      *(ushort4*)(prow + i * 4) = u;
    }
    ssum += __shfl_xor(ssum, 1);
    ssum += __shfl_xor(ssum, 2);
    if (qq == 0) rsum[row] = ssum;
  }
  __syncthreads();

  // O = P*V (64x64)
  f32x4 oa[2][2];
#pragma unroll
  for (int m = 0; m < 2; ++m)
#pragma unroll
    for (int n = 0; n < 2; ++n) oa[m][n] = (f32x4){0.f, 0.f, 0.f, 0.f};
#pragma unroll
  for (int kc = 0; kc < 4; ++kc) {
    bf16x8 aP[2], bV[2];
#pragma unroll
    for (int m = 0; m < 2; ++m)
      aP[m] = *(const bf16x8*)&Pl[(wr * 32 + m * 16 + fr) * 128 + kc * 32 + fq * 8];
#pragma unroll
    for (int n = 0; n < 2; ++n)
      bV[n] = *(const bf16x8*)&Vt[(wc * 32 + n * 16 + fr) * 128 + kc * 32 + fq * 8];
#pragma unroll
    for (int m = 0; m < 2; ++m)
#pragma unroll
      for (int n = 0; n < 2; ++n)
        oa[m][n] = __builtin_amdgcn_mfma_f32_16x16x32_bf16(aP[m], bV[n], oa[m][n], 0, 0, 0);
  }
#pragma unroll
  for (int m = 0; m < 2; ++m)
#pragma unroll
    for (int n = 0; n < 2; ++n)
#pragma unroll
      for (int r = 0; r < 4; ++r) {
        int row = wr * 32 + m * 16 + fq * 4 + r, col = wc * 32 + n * 16 + fr;
        Obuf[(rowQ + row) * 512 + h * 64 + col] = oa[m][n][r] / rsum[row];
      }
}

// ---------------- swish + LayerNorm over D=512 (wave per row), out bf16 ----------------
__global__ __launch_bounds__(256) void swish_ln(
    const float* __restrict__ O, ushort* __restrict__ X,
    const float* __restrict__ gamma, const float* __restrict__ beta)
{
  int row = blockIdx.x * 4 + (threadIdx.x >> 6);
  int lane = threadIdx.x & 63;
  const float* x = O + (size_t)row * 512 + lane * 8;
  float4 va = *(const float4*)(x);
  float4 vb = *(const float4*)(x + 4);
  float y[8] = {va.x, va.y, va.z, va.w, vb.x, vb.y, vb.z, vb.w};
  float s = 0.f, sq = 0.f;
#pragma unroll
  for (int i = 0; i < 8; ++i) {
    y[i] = y[i] / (1.f + __expf(-y[i]));
    s += y[i]; sq += y[i] * y[i];
  }
#pragma unroll
  for (int o = 1; o < 64; o <<= 1) { s += __shfl_xor(s, o); sq += __shfl_xor(sq, o); }
  float mean = s * (1.f / 512.f);
  float var = (sq - s * mean) * (1.f / 511.f);   // unbiased (ddof=1)
  float inv = 1.f / (sqrtf(var) + 1e-6f);
  const float4 g0 = *(const float4*)(gamma + lane * 8);
  const float4 g1 = *(const float4*)(gamma + lane * 8 + 4);
  const float4 b0 = *(const float4*)(beta + lane * 8);
  const float4 b1 = *(const float4*)(beta + lane * 8 + 4);
  float gg[8] = {g0.x, g0.y, g0.z, g0.w, g1.x, g1.y, g1.z, g1.w};
  float bb[8] = {b0.x, b0.y, b0.z, b0.w, b1.x, b1.y, b1.z, b1.w};
  ushort u[8];
#pragma unroll
  for (int i = 0; i < 8; ++i) u[i] = f2bf(gg[i] * (y[i] - mean) * inv + bb[i]);
  *(uint4*)(X + (size_t)row * 512 + lane * 8) = *(uint4*)u;
}

// ---------------- fc GEMM + residual + BN partial sums ----------------
__global__ __launch_bounds__(256) void gemm_fc(
    const ushort* __restrict__ A, const ushort* __restrict__ Bm,
    const float* __restrict__ resid, float* __restrict__ out,
    float* __restrict__ bn_sum, float* __restrict__ bn_sq)
{
  __shared__ __align__(16) ushort At[128 * 64];
  __shared__ __align__(16) ushort Bt[128 * 64];
  __shared__ float csum[128], csq[128];
  const int K = 512;
  int rowBase = blockIdx.x * 128;   // 16
  int colBase = blockIdx.y * 128;   // 32
  int tid = threadIdx.x, l = tid & 63, w = tid >> 6;
  int wr = w >> 1, wc = w & 1, fr = l & 15, fq = l >> 4;
  if (tid < 128) { csum[tid] = 0.f; csq[tid] = 0.f; }
  f32x4 acc[4][4];
#pragma unroll
  for (int m = 0; m < 4; ++m)
#pragma unroll
    for (int n = 0; n < 4; ++n) acc[m][n] = (f32x4){0.f, 0.f, 0.f, 0.f};

  for (int kt = 0; kt < K; kt += 64) {
#pragma unroll
    for (int j = 0; j < 4; ++j) {
      int c = ((w * 4 + j) << 6) + l;
      int row = c >> 3, cc = c & 7;
      __builtin_amdgcn_global_load_lds(AS1(A + (size_t)(rowBase + row) * K + kt + cc * 8),
                                       AS3((char*)At + (w * 4 + j) * 1024), 16, 0, 0);
      __builtin_amdgcn_global_load_lds(AS1(Bm + (size_t)(colBase + row) * K + kt + cc * 8),
                                       AS3((char*)Bt + (w * 4 + j) * 1024), 16, 0, 0);
    }
    __syncthreads();
#pragma unroll
    for (int kc = 0; kc < 2; ++kc) {
      bf16x8 af[4], bfv[4];
#pragma unroll
      for (int m = 0; m < 4; ++m)
        af[m] = *(const bf16x8*)&At[(wr * 64 + m * 16 + fr) * 64 + kc * 32 + fq * 8];
#pragma unroll
      for (int n = 0; n < 4; ++n)
        bfv[n] = *(const bf16x8*)&Bt[(wc * 64 + n * 16 + fr) * 64 + kc * 32 + fq * 8];
#pragma unroll
      for (int m = 0; m < 4; ++m)
#pragma unroll
        for (int n = 0; n < 4; ++n)
          acc[m][n] = __builtin_amdgcn_mfma_f32_16x16x32_bf16(af[m], bfv[n], acc[m][n], 0, 0, 0);
    }
    __syncthreads();
  }
  // epilogue: out = acc + residual; per-channel partial sums for BN
#pragma unroll
  for (int m = 0; m < 4; ++m)
#pragma unroll
    for (int r = 0; r < 4; ++r) {
      float ps = 0.f, pq = 0.f;
#pragma unroll
      for (int n = 0; n < 4; ++n) {
        int row = rowBase + wr * 64 + m * 16 + fq * 4 + r;
        int col = colBase + wc * 64 + n * 16 + fr;
        size_t idx = (size_t)row * 4096 + col;
        float val = acc[m][n][r] + resid[idx];
        out[idx] = val;
        ps += val; pq += val * val;
      }
#pragma unroll
      for (int o = 1; o < 16; o <<= 1) { ps += __shfl_xor(ps, o); pq += __shfl_xor(pq, o); }
      if (fr == 0) {
        int ch = wr * 64 + m * 16 + fq * 4 + r;   // rowBase % 128 == 0
        atomicAdd(&csum[ch], ps);
        atomicAdd(&csq[ch], pq);
      }
    }
  __syncthreads();
  if (tid < 128) {
    atomicAdd(&bn_sum[tid], csum[tid]);
    atomicAdd(&bn_sq[tid], csq[tid]);
  }
}

// ---------------- BatchNorm finalize (in place on d_out) ----------------
__global__ __launch_bounds__(256) void bn_norm(
    float* __restrict__ out, const float* __restrict__ bn_sum, const float* __restrict__ bn_sq,
    const float* __restrict__ gamma, const float* __restrict__ beta)
{
  const float inv_n = 1.f / 65536.f;
  int stride = gridDim.x * blockDim.x;
  for (int v = blockIdx.x * blockDim.x + threadIdx.x; v < 2097152; v += stride) {
    int elem = v * 4;
    int ch = (elem >> 12) & 127;
    float mean = bn_sum[ch] * inv_n;
    float var = bn_sq[ch] * inv_n - mean * mean;
    float g = gamma[ch] * rsqrtf(var + 1e-5f);
    float bta = beta[ch];
    float4 x = *(float4*)(out + elem);
    x.x = (x.x - mean) * g + bta;
    x.y = (x.y - mean) * g + bta;
    x.z = (x.z - mean) * g + bta;
    x.w = (x.w - mean) * g + bta;
    *(float4*)(out + elem) = x;
  }
}

extern "C" void kernel_launch(void* const* d_in, const int* in_sizes, int n_in,
                              void* d_out, int out_size, void* d_ws, size_t ws_size,
                              hipStream_t stream)
{
  const float* v_in = (const float*)d_in[0];
  const float* k_in = (const float*)d_in[1];
  const float* q_in = (const float*)d_in[2];
  const float* w_qs = (const float*)d_in[3];
  const float* w_ks = (const float*)d_in[4];
  const float* w_vs = (const float*)d_in[5];
  const float* w_fc = (const float*)d_in[6];
  const float* ln_g = (const float*)d_in[7];
  const float* ln_b = (const float*)d_in[8];
  const float* temp = (const float*)d_in[9];
  const float* bn_g = (const float*)d_in[10];
  const float* bn_b = (const float*)d_in[11];
  float* out = (float*)d_out;

  char* ws = (char*)d_ws;
  size_t off = 0;
  auto alloc = [&](size_t bytes) { char* p = ws + off; off += bytes; return p; };
  ushort* wq  = (ushort*)alloc(512ull * 4096 * 2);
  ushort* wk  = (ushort*)alloc(512ull * 4096 * 2);
  ushort* wv  = (ushort*)alloc(512ull * 4096 * 2);
  ushort* wfc = (ushort*)alloc(512ull * 4096 * 2);
  ushort* Qp  = (ushort*)alloc(2048ull * 512 * 2);
  ushort* Kp  = (ushort*)alloc(2048ull * 512 * 2);
  ushort* Vp  = (ushort*)alloc(2048ull * 512 * 2);
  float*  Obuf= (float*)alloc(2048ull * 512 * 4);
  ushort* X16 = (ushort*)alloc(2048ull * 512 * 2);
  float*  bns = (float*)alloc(128 * 4);
  float*  bnq = (float*)alloc(128 * 4);

  // split-K partial planes: 3*(1<<lgs) planes of 2048*512 fp32
  int lgs = 2;                       // 4-way split-K -> 768 blocks (~3 blocks/CU)
  if (off + (3ull << lgs) * 1048576 * 4 > ws_size) lgs = 1;
  if (off + (3ull << lgs) * 1048576 * 4 > ws_size) lgs = 0;
  float* part = (float*)alloc((3ull << lgs) * 1048576 * 4);

  hipMemsetAsync(bns, 0, 256 * 4, stream);   // zero bns+bnq (adjacent)

  pack4<<<dim3(512, 4), 256, 0, stream>>>(w_qs, w_ks, w_vs, w_fc, wq, wk, wv, wfc,
                                          512 * 4096);
  gemm_qkv<<<16 * 4 * (3 << lgs), 256, 0, stream>>>(q_in, k_in, v_in, wq, wk, wv, part, lgs);
  reduce_qkv<<<dim3(1024, 3), 256, 0, stream>>>(part, Qp, Kp, Vp, lgs);
  attn<<<dim3(2, 128), 256, 0, stream>>>(Qp, Kp, Vp, Obuf, temp);
  swish_ln<<<512, 256, 0, stream>>>(Obuf, X16, ln_g, ln_b);
  gemm_fc<<<dim3(16, 32), 256, 0, stream>>>(X16, wfc, v_in, out, bns, bnq);
  bn_norm<<<2048, 256, 0, stream>>>(out, bns, bnq, bn_g, bn_b);
}

// Round 9
// 115.974 us; speedup vs baseline: 2.0009x; 2.0009x over previous
//
#include <hip/hip_runtime.h>
#include <hip/hip_bf16.h>
#include <stdint.h>

typedef __attribute__((ext_vector_type(8))) short bf16x8;
typedef __attribute__((ext_vector_type(4))) float f32x4;

#define AS1(p) ((const __attribute__((address_space(1))) uint32_t*)(p))
#define AS3(p) ((__attribute__((address_space(3))) uint32_t*)(p))

__device__ __forceinline__ ushort f2bf(float f) {
  uint32_t u = __float_as_uint(f);
  uint32_t r = (u + 0x7fffu + ((u >> 16) & 1u)) >> 16;
  return (ushort)r;
}

__device__ __forceinline__ float bf2f(ushort u) {
  uint32_t v = ((uint32_t)u) << 16;
  return __uint_as_float(v);
}

// fp32x8 -> bf16x8 via packed cvt (RTNE)
__device__ __forceinline__ uint4 cvt8u(float4 a0, float4 a1) {
  uint4 r;
  asm("v_cvt_pk_bf16_f32 %0, %1, %2" : "=v"(r.x) : "v"(a0.x), "v"(a0.y));
  asm("v_cvt_pk_bf16_f32 %0, %1, %2" : "=v"(r.y) : "v"(a0.z), "v"(a0.w));
  asm("v_cvt_pk_bf16_f32 %0, %1, %2" : "=v"(r.z) : "v"(a1.x), "v"(a1.y));
  asm("v_cvt_pk_bf16_f32 %0, %1, %2" : "=v"(r.w) : "v"(a1.z), "v"(a1.w));
  return r;
}

// ---------------- pack: fp32 -> bf16 (weights only) ----------------
__global__ __launch_bounds__(256) void pack4(
    const float* __restrict__ s0, const float* __restrict__ s1,
    const float* __restrict__ s2, const float* __restrict__ s3,
    ushort* __restrict__ o0, ushort* __restrict__ o1,
    ushort* __restrict__ o2, ushort* __restrict__ o3, int n)
{
  const float* s; ushort* o;
  switch (blockIdx.y) {
    case 0: s = s0; o = o0; break;
    case 1: s = s1; o = o1; break;
    case 2: s = s2; o = o2; break;
    default: s = s3; o = o3; break;
  }
  int stride = gridDim.x * 1024;
  for (int i = (blockIdx.x * 256 + threadIdx.x) * 4; i < n; i += stride) {
    float4 v = *(const float4*)(s + i);
    ushort4 u;
    u.x = f2bf(v.x); u.y = f2bf(v.y); u.z = f2bf(v.z); u.w = f2bf(v.w);
    *(ushort4*)(o + i) = u;
  }
}

// ---------------- QKV projection GEMM, split-K, T14+T2 structure (r7, proven) ----------------
// C[2048,512] = A[2048,4096](fp32) * W[512,4096]^T(bf16) for 3 (A,W) pairs.
// A: global fp32 -> regs (issued pre-MFMA, latency covered by MFMA) -> cvt_pk
//    -> swizzled ds_write bf16 AFTER barrier-1 (T14 write-late). At = 16KB.
// B: bf16 weights via global_load_lds, double-buffered Bt, pre-swizzled global
//    source (linear LDS dest). T2 swizzle verified conflict-free (r7: 0 conflicts).
// Partials now bf16 (halves split-K write traffic).
__global__ __launch_bounds__(256) void gemm_qkv(
    const float* __restrict__ aq, const float* __restrict__ ak, const float* __restrict__ av,
    const ushort* __restrict__ wq, const ushort* __restrict__ wk, const ushort* __restrict__ wv,
    ushort* __restrict__ part, int lgs)
{
  __shared__ __align__(16) ushort At[128 * 64];        // 16KB bf16 (single buf)
  __shared__ __align__(16) ushort Bt[2][128 * 64];     // 2x16KB bf16
  int per = gridDim.x >> 3;
  int bid = blockIdx.x;
  int swz = (bid & 7) * per + (bid >> 3);
  int y = swz & 3, x = (swz >> 2) & 15, zz = swz >> 6;
  int g = zz >> lgs, s = zz & ((1 << lgs) - 1);
  const float* A; const ushort* Bm;
  if (g == 0)      { A = aq; Bm = wq; }
  else if (g == 1) { A = ak; Bm = wk; }
  else             { A = av; Bm = wv; }
  ushort* Pd = part + ((size_t)zz) * 1048576;   // plane 2048*512 bf16
  const int K = 4096;
  const int kchunk = K >> lgs;
  const int k0 = s * kchunk, kend = k0 + kchunk;
  int rowBase = x * 128;
  int colBase = y * 128;
  int tid = threadIdx.x, l = tid & 63, w = tid >> 6;
  int wr = w >> 1, wc = w & 1, fr = l & 15, fq = l >> 4;

  // A staging map: thread t covers rows {j*32 + t>>3}, col-slot t&7 (32B of fp32)
  int arow = tid >> 3;
  int aslot = tid & 7;
  const float* Abase = A + (size_t)(rowBase + arow) * K + aslot * 8;

  f32x4 acc[4][4];
#pragma unroll
  for (int m = 0; m < 4; ++m)
#pragma unroll
    for (int n = 0; n < 4; ++n) acc[m][n] = (f32x4){0.f, 0.f, 0.f, 0.f};

  float4 areg[4][2];
  auto loadA = [&](int ktn) {
#pragma unroll
    for (int j = 0; j < 4; ++j) {
      const float* p = Abase + (size_t)(j * 32) * K + ktn;
      areg[j][0] = *(const float4*)p;
      areg[j][1] = *(const float4*)(p + 4);
    }
  };
  auto cvtWriteA = [&]() {
#pragma unroll
    for (int j = 0; j < 4; ++j) {
      int row = j * 32 + arow;
      int sw = aslot ^ (row & 7);
      *(uint4*)((char*)At + row * 128 + sw * 16) = cvt8u(areg[j][0], areg[j][1]);
    }
  };
  auto stageB = [&](ushort* Bbuf, int ktn) {
#pragma unroll
    for (int j = 0; j < 4; ++j) {
      int c = ((w * 4 + j) << 6) + l;      // 0..1023 16B-chunk (linear LDS dest)
      int row = c >> 3, slot = c & 7;
      int srccol = (slot ^ (row & 7)) * 8; // pre-swizzled global source (bf16 elems)
      __builtin_amdgcn_global_load_lds(AS1(Bm + (size_t)(colBase + row) * K + ktn + srccol),
                                       AS3((char*)Bbuf + c * 16), 16, 0, 0);
    }
  };
  auto mfmaPhase = [&](const ushort* Bbuf) {
#pragma unroll
    for (int kc = 0; kc < 2; ++kc) {
      bf16x8 af[4], bv[4];
#pragma unroll
      for (int m = 0; m < 4; ++m) {
        int r = wr * 64 + m * 16 + fr;
        int sl = (kc * 4 + fq) ^ (fr & 7);
        af[m] = *(const bf16x8*)((const char*)At + r * 128 + sl * 16);
      }
#pragma unroll
      for (int n = 0; n < 4; ++n) {
        int r = wc * 64 + n * 16 + fr;
        int sl = (kc * 4 + fq) ^ (fr & 7);
        bv[n] = *(const bf16x8*)((const char*)Bbuf + r * 128 + sl * 16);
      }
#pragma unroll
      for (int m = 0; m < 4; ++m)
#pragma unroll
        for (int n = 0; n < 4; ++n)
          acc[m][n] = __builtin_amdgcn_mfma_f32_16x16x32_bf16(af[m], bv[n], acc[m][n], 0, 0, 0);
    }
  };

  // prologue: fill At(k0), Bt[0](k0)
  loadA(k0);
  stageB(Bt[0], k0);
  cvtWriteA();
  __syncthreads();

  int buf = 0;
#pragma unroll 1
  for (int kt = k0; kt < kend; kt += 64) {
    bool more = (kt + 64) < kend;
    if (more) { loadA(kt + 64); stageB(Bt[buf ^ 1], kt + 64); }  // in flight under MFMA
    mfmaPhase(Bt[buf]);
    __syncthreads();             // b1: At readers done; drains loads (covered by MFMA)
    if (more) cvtWriteA();       // T14 write-late: regs -> swizzled At
    __syncthreads();             // b2: ds_writes visible
    buf ^= 1;
  }

#pragma unroll
  for (int m = 0; m < 4; ++m)
#pragma unroll
    for (int n = 0; n < 4; ++n)
#pragma unroll
      for (int r = 0; r < 4; ++r) {
        int row = rowBase + wr * 64 + m * 16 + fq * 4 + r;
        int col = colBase + wc * 64 + n * 16 + fr;
        Pd[(size_t)row * 512 + col] = f2bf(acc[m][n][r]);
      }
}

// ---------------- reduce split-K bf16 partials -> bf16 Q/K/V ----------------
__global__ __launch_bounds__(256) void reduce_qkv(
    const ushort* __restrict__ part, ushort* __restrict__ Qp, ushort* __restrict__ Kp,
    ushort* __restrict__ Vp, int lgs)
{
  int g = blockIdx.y;
  ushort* dst = g == 0 ? Qp : (g == 1 ? Kp : Vp);
  const ushort* p = part + (((size_t)g) << lgs) * 1048576;
  int i = (blockIdx.x * 256 + threadIdx.x) * 8;
  int splits = 1 << lgs;
  float accv[8];
  {
    bf16x8 v = *(const bf16x8*)(p + i);
#pragma unroll
    for (int j = 0; j < 8; ++j) accv[j] = bf2f((ushort)v[j]);
  }
  for (int s = 1; s < splits; ++s) {
    bf16x8 v = *(const bf16x8*)(p + (size_t)s * 1048576 + i);
#pragma unroll
    for (int j = 0; j < 8; ++j) accv[j] += bf2f((ushort)v[j]);
  }
  ushort u[8];
#pragma unroll
  for (int j = 0; j < 8; ++j) u[j] = f2bf(accv[j]);
  *(uint4*)(dst + i) = *(uint4*)u;
}

// ---------------- attention: per (b,h, row-half) block ----------------
__global__ __launch_bounds__(256) void attn(
    const ushort* __restrict__ Qp, const ushort* __restrict__ Kp, const ushort* __restrict__ Vp,
    float* __restrict__ Obuf, const float* __restrict__ temp)
{
  __shared__ __align__(16) ushort Qs[64 * 64];    // [crow][d]
  __shared__ __align__(16) ushort Ks[128 * 64];   // [e][d]
  __shared__ __align__(16) ushort Vt[64 * 128];   // [d][e] (transposed)
  __shared__ __align__(16) float  Sl[64 * 128];   // scores
  __shared__ __align__(16) ushort Pl[64 * 128];   // exp(S-max) bf16
  __shared__ float rsum[64];
  int bh = blockIdx.y, b = bh >> 3, h = bh & 7;
  int c0 = blockIdx.x * 64;
  int tid = threadIdx.x, l = tid & 63, w = tid >> 6;
  int wr = w >> 1, wc = w & 1, fr = l & 15, fq = l >> 4;
  float invT = 1.0f / temp[0];
  const size_t rowQ = (size_t)(b * 128 + c0);

  // stage Q (64 rows x 64 d)
#pragma unroll
  for (int j = 0; j < 2; ++j) {
    int c = ((w * 2 + j) << 6) + l, row = c >> 3, cc = c & 7;
    __builtin_amdgcn_global_load_lds(AS1(Qp + (rowQ + row) * 512 + h * 64 + cc * 8),
                                     AS3((char*)Qs + (w * 2 + j) * 1024), 16, 0, 0);
  }
  // stage K (128 rows x 64 d)
#pragma unroll
  for (int j = 0; j < 4; ++j) {
    int c = ((w * 4 + j) << 6) + l, row = c >> 3, cc = c & 7;
    __builtin_amdgcn_global_load_lds(AS1(Kp + (size_t)(b * 128 + row) * 512 + h * 64 + cc * 8),
                                     AS3((char*)Ks + (w * 4 + j) * 1024), 16, 0, 0);
  }
  // stage V transposed: Vt[d][e]
#pragma unroll
  for (int t = 0; t < 4; ++t) {
    int ch = tid + t * 256, e = ch >> 3, d0 = (ch & 7) * 8;
    bf16x8 vv = *(const bf16x8*)(Vp + (size_t)(b * 128 + e) * 512 + h * 64 + d0);
#pragma unroll
    for (int j = 0; j < 8; ++j) Vt[(d0 + j) * 128 + e] = (ushort)vv[j];
  }
  __syncthreads();

  // S = Q*K^T (64x128)
  f32x4 sa[2][4];
#pragma unroll
  for (int m = 0; m < 2; ++m)
#pragma unroll
    for (int n = 0; n < 4; ++n) sa[m][n] = (f32x4){0.f, 0.f, 0.f, 0.f};
#pragma unroll
  for (int kc = 0; kc < 2; ++kc) {
    bf16x8 aQ[2], bK[4];
#pragma unroll
    for (int m = 0; m < 2; ++m)
      aQ[m] = *(const bf16x8*)&Qs[(wr * 32 + m * 16 + fr) * 64 + kc * 32 + fq * 8];
#pragma unroll
    for (int n = 0; n < 4; ++n)
      bK[n] = *(const bf16x8*)&Ks[(wc * 64 + n * 16 + fr) * 64 + kc * 32 + fq * 8];
#pragma unroll
    for (int m = 0; m < 2; ++m)
#pragma unroll
      for (int n = 0; n < 4; ++n)
        sa[m][n] = __builtin_amdgcn_mfma_f32_16x16x32_bf16(aQ[m], bK[n], sa[m][n], 0, 0, 0);
  }
#pragma unroll
  for (int m = 0; m < 2; ++m)
#pragma unroll
    for (int n = 0; n < 4; ++n)
#pragma unroll
      for (int r = 0; r < 4; ++r)
        Sl[(wr * 32 + m * 16 + fq * 4 + r) * 128 + wc * 64 + n * 16 + fr] = sa[m][n][r] * invT;
  __syncthreads();

  // softmax: 4 threads per row, 32 cols each
  {
    int row = tid >> 2, qq = tid & 3;
    const float* srow = Sl + row * 128 + qq * 32;
    float4 va[8];
#pragma unroll
    for (int i = 0; i < 8; ++i) va[i] = *(const float4*)(srow + i * 4);
    float mx = -1e30f;
#pragma unroll
    for (int i = 0; i < 8; ++i)
      mx = fmaxf(mx, fmaxf(fmaxf(va[i].x, va[i].y), fmaxf(va[i].z, va[i].w)));
    mx = fmaxf(mx, __shfl_xor(mx, 1));
    mx = fmaxf(mx, __shfl_xor(mx, 2));
    float ssum = 0.f;
    ushort* prow = Pl + row * 128 + qq * 32;
#pragma unroll
    for (int i = 0; i < 8; ++i) {
      float e0 = __expf(va[i].x - mx), e1 = __expf(va[i].y - mx);
      float e2 = __expf(va[i].z - mx), e3 = __expf(va[i].w - mx);
      ssum += (e0 + e1) + (e2 + e3);
      ushort4 u; u.x = f2bf(e0); u.y = f2bf(e1); u.z = f2bf(e2); u.w = f2bf(e3);
      *(ushort4*)(prow + i * 4) = u;
    }
    ssum += __shfl_xor(ssum, 1);
    ssum += __shfl_xor(ssum, 2);
    if (qq == 0) rsum[row] = ssum;
  }
  __syncthreads();

  // O = P*V (64x64)
  f32x4 oa[2][2];
#pragma unroll
  for (int m = 0; m < 2; ++m)
#pragma unroll
    for (int n = 0; n < 2; ++n) oa[m][n] = (f32x4){0.f, 0.f, 0.f, 0.f};
#pragma unroll
  for (int kc = 0; kc < 4; ++kc) {
    bf16x8 aP[2], bV[2];
#pragma unroll
    for (int m = 0; m < 2; ++m)
      aP[m] = *(const bf16x8*)&Pl[(wr * 32 + m * 16 + fr) * 128 + kc * 32 + fq * 8];
#pragma unroll
    for (int n = 0; n < 2; ++n)
      bV[n] = *(const bf16x8*)&Vt[(wc * 32 + n * 16 + fr) * 128 + kc * 32 + fq * 8];
#pragma unroll
    for (int m = 0; m < 2; ++m)
#pragma unroll
      for (int n = 0; n < 2; ++n)
        oa[m][n] = __builtin_amdgcn_mfma_f32_16x16x32_bf16(aP[m], bV[n], oa[m][n], 0, 0, 0);
  }
#pragma unroll
  for (int m = 0; m < 2; ++m)
#pragma unroll
    for (int n = 0; n < 2; ++n)
#pragma unroll
      for (int r = 0; r < 4; ++r) {
        int row = wr * 32 + m * 16 + fq * 4 + r, col = wc * 32 + n * 16 + fr;
        Obuf[(rowQ + row) * 512 + h * 64 + col] = oa[m][n][r] / rsum[row];
      }
}

// ---------------- swish + LayerNorm over D=512 (wave per row), out bf16 ----------------
__global__ __launch_bounds__(256) void swish_ln(
    const float* __restrict__ O, ushort* __restrict__ X,
    const float* __restrict__ gamma, const float* __restrict__ beta)
{
  int row = blockIdx.x * 4 + (threadIdx.x >> 6);
  int lane = threadIdx.x & 63;
  const float* x = O + (size_t)row * 512 + lane * 8;
  float4 va = *(const float4*)(x);
  float4 vb = *(const float4*)(x + 4);
  float y[8] = {va.x, va.y, va.z, va.w, vb.x, vb.y, vb.z, vb.w};
  float s = 0.f, sq = 0.f;
#pragma unroll
  for (int i = 0; i < 8; ++i) {
    y[i] = y[i] / (1.f + __expf(-y[i]));
    s += y[i]; sq += y[i] * y[i];
  }
#pragma unroll
  for (int o = 1; o < 64; o <<= 1) { s += __shfl_xor(s, o); sq += __shfl_xor(sq, o); }
  float mean = s * (1.f / 512.f);
  float var = (sq - s * mean) * (1.f / 511.f);   // unbiased (ddof=1)
  float inv = 1.f / (sqrtf(var) + 1e-6f);
  const float4 g0 = *(const float4*)(gamma + lane * 8);
  const float4 g1 = *(const float4*)(gamma + lane * 8 + 4);
  const float4 b0 = *(const float4*)(beta + lane * 8);
  const float4 b1 = *(const float4*)(beta + lane * 8 + 4);
  float gg[8] = {g0.x, g0.y, g0.z, g0.w, g1.x, g1.y, g1.z, g1.w};
  float bb[8] = {b0.x, b0.y, b0.z, b0.w, b1.x, b1.y, b1.z, b1.w};
  ushort u[8];
#pragma unroll
  for (int i = 0; i < 8; ++i) u[i] = f2bf(gg[i] * (y[i] - mean) * inv + bb[i]);
  *(uint4*)(X + (size_t)row * 512 + lane * 8) = *(uint4*)u;
}

// ---------------- fc GEMM + residual + BN partial sums ----------------
__global__ __launch_bounds__(256) void gemm_fc(
    const ushort* __restrict__ A, const ushort* __restrict__ Bm,
    const float* __restrict__ resid, float* __restrict__ out,
    float* __restrict__ bn_sum, float* __restrict__ bn_sq)
{
  __shared__ __align__(16) ushort At[128 * 64];
  __shared__ __align__(16) ushort Bt[128 * 64];
  __shared__ float csum[128], csq[128];
  const int K = 512;
  int rowBase = blockIdx.x * 128;   // 16
  int colBase = blockIdx.y * 128;   // 32
  int tid = threadIdx.x, l = tid & 63, w = tid >> 6;
  int wr = w >> 1, wc = w & 1, fr = l & 15, fq = l >> 4;
  if (tid < 128) { csum[tid] = 0.f; csq[tid] = 0.f; }
  f32x4 acc[4][4];
#pragma unroll
  for (int m = 0; m < 4; ++m)
#pragma unroll
    for (int n = 0; n < 4; ++n) acc[m][n] = (f32x4){0.f, 0.f, 0.f, 0.f};

  for (int kt = 0; kt < K; kt += 64) {
#pragma unroll
    for (int j = 0; j < 4; ++j) {
      int c = ((w * 4 + j) << 6) + l;
      int row = c >> 3, cc = c & 7;
      __builtin_amdgcn_global_load_lds(AS1(A + (size_t)(rowBase + row) * K + kt + cc * 8),
                                       AS3((char*)At + (w * 4 + j) * 1024), 16, 0, 0);
      __builtin_amdgcn_global_load_lds(AS1(Bm + (size_t)(colBase + row) * K + kt + cc * 8),
                                       AS3((char*)Bt + (w * 4 + j) * 1024), 16, 0, 0);
    }
    __syncthreads();
#pragma unroll
    for (int kc = 0; kc < 2; ++kc) {
      bf16x8 af[4], bfv[4];
#pragma unroll
      for (int m = 0; m < 4; ++m)
        af[m] = *(const bf16x8*)&At[(wr * 64 + m * 16 + fr) * 64 + kc * 32 + fq * 8];
#pragma unroll
      for (int n = 0; n < 4; ++n)
        bfv[n] = *(const bf16x8*)&Bt[(wc * 64 + n * 16 + fr) * 64 + kc * 32 + fq * 8];
#pragma unroll
      for (int m = 0; m < 4; ++m)
#pragma unroll
        for (int n = 0; n < 4; ++n)
          acc[m][n] = __builtin_amdgcn_mfma_f32_16x16x32_bf16(af[m], bfv[n], acc[m][n], 0, 0, 0);
    }
    __syncthreads();
  }
  // epilogue: out = acc + residual; per-channel partial sums for BN
#pragma unroll
  for (int m = 0; m < 4; ++m)
#pragma unroll
    for (int r = 0; r < 4; ++r) {
      float ps = 0.f, pq = 0.f;
#pragma unroll
      for (int n = 0; n < 4; ++n) {
        int row = rowBase + wr * 64 + m * 16 + fq * 4 + r;
        int col = colBase + wc * 64 + n * 16 + fr;
        size_t idx = (size_t)row * 4096 + col;
        float val = acc[m][n][r] + resid[idx];
        out[idx] = val;
        ps += val; pq += val * val;
      }
#pragma unroll
      for (int o = 1; o < 16; o <<= 1) { ps += __shfl_xor(ps, o); pq += __shfl_xor(pq, o); }
      if (fr == 0) {
        int ch = wr * 64 + m * 16 + fq * 4 + r;   // rowBase % 128 == 0
        atomicAdd(&csum[ch], ps);
        atomicAdd(&csq[ch], pq);
      }
    }
  __syncthreads();
  if (tid < 128) {
    atomicAdd(&bn_sum[tid], csum[tid]);
    atomicAdd(&bn_sq[tid], csq[tid]);
  }
}

// ---------------- BatchNorm finalize (in place on d_out) ----------------
__global__ __launch_bounds__(256) void bn_norm(
    float* __restrict__ out, const float* __restrict__ bn_sum, const float* __restrict__ bn_sq,
    const float* __restrict__ gamma, const float* __restrict__ beta)
{
  __shared__ float sc[128], sh[128];
  const float inv_n = 1.f / 65536.f;
  int tid = threadIdx.x;
  if (tid < 128) {
    float mean = bn_sum[tid] * inv_n;
    float var = bn_sq[tid] * inv_n - mean * mean;
    float g = gamma[tid] * rsqrtf(var + 1e-5f);
    sc[tid] = g;
    sh[tid] = beta[tid] - mean * g;
  }
  __syncthreads();
  int stride = gridDim.x * blockDim.x;
  for (int v = blockIdx.x * blockDim.x + tid; v < 2097152; v += stride) {
    int elem = v * 4;
    int ch = (elem >> 12) & 127;
    float g = sc[ch], bta = sh[ch];
    float4 x = *(float4*)(out + elem);
    x.x = x.x * g + bta;
    x.y = x.y * g + bta;
    x.z = x.z * g + bta;
    x.w = x.w * g + bta;
    *(float4*)(out + elem) = x;
  }
}

extern "C" void kernel_launch(void* const* d_in, const int* in_sizes, int n_in,
                              void* d_out, int out_size, void* d_ws, size_t ws_size,
                              hipStream_t stream)
{
  const float* v_in = (const float*)d_in[0];
  const float* k_in = (const float*)d_in[1];
  const float* q_in = (const float*)d_in[2];
  const float* w_qs = (const float*)d_in[3];
  const float* w_ks = (const float*)d_in[4];
  const float* w_vs = (const float*)d_in[5];
  const float* w_fc = (const float*)d_in[6];
  const float* ln_g = (const float*)d_in[7];
  const float* ln_b = (const float*)d_in[8];
  const float* temp = (const float*)d_in[9];
  const float* bn_g = (const float*)d_in[10];
  const float* bn_b = (const float*)d_in[11];
  float* out = (float*)d_out;

  char* ws = (char*)d_ws;
  size_t off = 0;
  auto alloc = [&](size_t bytes) { char* p = ws + off; off += bytes; return p; };
  ushort* wq  = (ushort*)alloc(512ull * 4096 * 2);
  ushort* wk  = (ushort*)alloc(512ull * 4096 * 2);
  ushort* wv  = (ushort*)alloc(512ull * 4096 * 2);
  ushort* wfc = (ushort*)alloc(512ull * 4096 * 2);
  ushort* Qp  = (ushort*)alloc(2048ull * 512 * 2);
  ushort* Kp  = (ushort*)alloc(2048ull * 512 * 2);
  ushort* Vp  = (ushort*)alloc(2048ull * 512 * 2);
  float*  Obuf= (float*)alloc(2048ull * 512 * 4);
  ushort* X16 = (ushort*)alloc(2048ull * 512 * 2);
  float*  bns = (float*)alloc(128 * 4);
  float*  bnq = (float*)alloc(128 * 4);

  // split-K partial planes: 3*(1<<lgs) planes of 2048*512 bf16
  int lgs = 2;                       // 4-way split-K -> 768 blocks (~3 blocks/CU)
  if (off + (3ull << lgs) * 1048576 * 2 > ws_size) lgs = 1;
  if (off + (3ull << lgs) * 1048576 * 2 > ws_size) lgs = 0;
  ushort* part = (ushort*)alloc((3ull << lgs) * 1048576 * 2);

  hipMemsetAsync(bns, 0, 256 * 4, stream);   // zero bns+bnq (adjacent)

  pack4<<<dim3(512, 4), 256, 0, stream>>>(w_qs, w_ks, w_vs, w_fc, wq, wk, wv, wfc,
                                          512 * 4096);
  gemm_qkv<<<16 * 4 * (3 << lgs), 256, 0, stream>>>(q_in, k_in, v_in, wq, wk, wv, part, lgs);
  reduce_qkv<<<dim3(512, 3), 256, 0, stream>>>(part, Qp, Kp, Vp, lgs);
  attn<<<dim3(2, 128), 256, 0, stream>>>(Qp, Kp, Vp, Obuf, temp);
  swish_ln<<<512, 256, 0, stream>>>(Obuf, X16, ln_g, ln_b);
  gemm_fc<<<dim3(16, 32), 256, 0, stream>>>(X16, wfc, v_in, out, bns, bnq);
  bn_norm<<<2048, 256, 0, stream>>>(out, bns, bnq, bn_g, bn_b);
}

// Round 10
// 114.755 us; speedup vs baseline: 2.0221x; 1.0106x over previous
//
#include <hip/hip_runtime.h>
#include <hip/hip_bf16.h>
#include <stdint.h>

typedef __attribute__((ext_vector_type(8))) short bf16x8;
typedef __attribute__((ext_vector_type(4))) float f32x4;

#define AS1(p) ((const __attribute__((address_space(1))) uint32_t*)(p))
#define AS3(p) ((__attribute__((address_space(3))) uint32_t*)(p))

// counted waits: NO clobbers (clobbers forced r8's prefetch regs to scratch);
// volatile + sched_barrier(0) pins ordering (rule #18)
#define VM12   asm volatile("s_waitcnt vmcnt(12)")
#define VM0    asm volatile("s_waitcnt vmcnt(0)")
#define LG0    asm volatile("s_waitcnt lgkmcnt(0)")
#define SBAR   __builtin_amdgcn_s_barrier()
#define SCHED0 __builtin_amdgcn_sched_barrier(0)

__device__ __forceinline__ ushort f2bf(float f) {
  uint32_t u = __float_as_uint(f);
  uint32_t r = (u + 0x7fffu + ((u >> 16) & 1u)) >> 16;
  return (ushort)r;
}

__device__ __forceinline__ float bf2f(ushort u) {
  uint32_t v = ((uint32_t)u) << 16;
  return __uint_as_float(v);
}

// fp32x8 -> bf16x8 via packed cvt (RTNE)
__device__ __forceinline__ uint4 cvt8u(float4 a0, float4 a1) {
  uint4 r;
  asm("v_cvt_pk_bf16_f32 %0, %1, %2" : "=v"(r.x) : "v"(a0.x), "v"(a0.y));
  asm("v_cvt_pk_bf16_f32 %0, %1, %2" : "=v"(r.y) : "v"(a0.z), "v"(a0.w));
  asm("v_cvt_pk_bf16_f32 %0, %1, %2" : "=v"(r.z) : "v"(a1.x), "v"(a1.y));
  asm("v_cvt_pk_bf16_f32 %0, %1, %2" : "=v"(r.w) : "v"(a1.z), "v"(a1.w));
  return r;
}

// ---------------- pack: fp32 -> bf16 (weights only) ----------------
__global__ __launch_bounds__(256) void pack4(
    const float* __restrict__ s0, const float* __restrict__ s1,
    const float* __restrict__ s2, const float* __restrict__ s3,
    ushort* __restrict__ o0, ushort* __restrict__ o1,
    ushort* __restrict__ o2, ushort* __restrict__ o3, int n)
{
  const float* s; ushort* o;
  switch (blockIdx.y) {
    case 0: s = s0; o = o0; break;
    case 1: s = s1; o = o1; break;
    case 2: s = s2; o = o2; break;
    default: s = s3; o = o3; break;
  }
  int stride = gridDim.x * 1024;
  for (int i = (blockIdx.x * 256 + threadIdx.x) * 4; i < n; i += stride) {
    float4 v = *(const float4*)(s + i);
    ushort4 u;
    u.x = f2bf(v.x); u.y = f2bf(v.y); u.z = f2bf(v.z); u.w = f2bf(v.w);
    *(ushort4*)(o + i) = u;
  }
}

// ---------------- QKV projection GEMM: r7 data paths + T4 counted-vmcnt sync ----------------
// A: fp32 global -> NAMED float4 regs a0..a7 (SSA, never address-taken) -> cvt_pk
//    -> swizzled ds_write bf16 At. B: bf16 weights via global_load_lds,
//    pre-swizzled source, double-buffered Bt. Raw s_barrier + manual vmcnt(12):
//    this iter's 12 issues stay in flight across both barriers (~1 full iter cover);
//    compiler auto-inserts vmcnt(4) before the cvt use of a0..a7.
__global__ __launch_bounds__(256, 3) void gemm_qkv(
    const float* __restrict__ aq, const float* __restrict__ ak, const float* __restrict__ av,
    const ushort* __restrict__ wq, const ushort* __restrict__ wk, const ushort* __restrict__ wv,
    ushort* __restrict__ part, int lgs)
{
  __shared__ __align__(16) ushort At[128 * 64];        // 16KB bf16
  __shared__ __align__(16) ushort Bt[2][128 * 64];     // 2x16KB bf16
  int per = gridDim.x >> 3;
  int bid = blockIdx.x;
  int swz = (bid & 7) * per + (bid >> 3);
  int y = swz & 3, x = (swz >> 2) & 15, zz = swz >> 6;
  int g = zz >> lgs, s = zz & ((1 << lgs) - 1);
  const float* A; const ushort* Bm;
  if (g == 0)      { A = aq; Bm = wq; }
  else if (g == 1) { A = ak; Bm = wk; }
  else             { A = av; Bm = wv; }
  ushort* Pd = part + ((size_t)zz) * 1048576;   // plane 2048*512 bf16
  const int K = 4096;
  const int kchunk = K >> lgs;
  const int k0 = s * kchunk, kend = k0 + kchunk;
  int rowBase = x * 128;
  int colBase = y * 128;
  int tid = threadIdx.x, l = tid & 63, w = tid >> 6;
  int wr = w >> 1, wc = w & 1, fr = l & 15, fq = l >> 4;

  int arow = tid >> 3;                 // 0..31
  int aslot = tid & 7;                 // 32B granule
  int aswz = aslot ^ (arow & 7);       // swizzled slot (same for all 4 row-groups)
  const float* Abase = A + (size_t)(rowBase + arow) * K + aslot * 8;
  char* At0 = (char*)At + arow * 128 + aswz * 16;

  f32x4 acc[4][4];
#pragma unroll
  for (int m = 0; m < 4; ++m)
#pragma unroll
    for (int n = 0; n < 4; ++n) acc[m][n] = (f32x4){0.f, 0.f, 0.f, 0.f};

  float4 a0, a1, a2, a3, a4, a5, a6, a7;   // named SSA prefetch regs

#define LOADA(ktn) do { \
    a0 = *(const float4*)(Abase + (size_t)0 * K + (ktn)); \
    a1 = *(const float4*)(Abase + (size_t)0 * K + (ktn) + 4); \
    a2 = *(const float4*)(Abase + (size_t)32 * K + (ktn)); \
    a3 = *(const float4*)(Abase + (size_t)32 * K + (ktn) + 4); \
    a4 = *(const float4*)(Abase + (size_t)64 * K + (ktn)); \
    a5 = *(const float4*)(Abase + (size_t)64 * K + (ktn) + 4); \
    a6 = *(const float4*)(Abase + (size_t)96 * K + (ktn)); \
    a7 = *(const float4*)(Abase + (size_t)96 * K + (ktn) + 4); \
  } while (0)

#define CVTWRITEA do { \
    *(uint4*)(At0 + 0 * 4096)  = cvt8u(a0, a1); \
    *(uint4*)(At0 + 1 * 4096)  = cvt8u(a2, a3); \
    *(uint4*)(At0 + 2 * 4096)  = cvt8u(a4, a5); \
    *(uint4*)(At0 + 3 * 4096)  = cvt8u(a6, a7); \
  } while (0)

#define STAGEB(bufIdx, ktn) do { \
    char* Bbuf_ = (char*)Bt[bufIdx]; \
    _Pragma("unroll") \
    for (int j = 0; j < 4; ++j) { \
      int c = ((w * 4 + j) << 6) + l; \
      int row = c >> 3, slot = c & 7; \
      int srccol = (slot ^ (row & 7)) * 8; \
      __builtin_amdgcn_global_load_lds(AS1(Bm + (size_t)(colBase + row) * K + (ktn) + srccol), \
                                       AS3(Bbuf_ + c * 16), 16, 0, 0); \
    } \
  } while (0)

#define MFMAPHASE(bufIdx) do { \
    const char* Bbuf_ = (const char*)Bt[bufIdx]; \
    _Pragma("unroll") \
    for (int kc = 0; kc < 2; ++kc) { \
      bf16x8 af[4], bv[4]; \
      _Pragma("unroll") \
      for (int m = 0; m < 4; ++m) { \
        int r = wr * 64 + m * 16 + fr; \
        int sl = (kc * 4 + fq) ^ (fr & 7); \
        af[m] = *(const bf16x8*)((const char*)At + r * 128 + sl * 16); \
      } \
      _Pragma("unroll") \
      for (int n = 0; n < 4; ++n) { \
        int r = wc * 64 + n * 16 + fr; \
        int sl = (kc * 4 + fq) ^ (fr & 7); \
        bv[n] = *(const bf16x8*)(Bbuf_ + r * 128 + sl * 16); \
      } \
      _Pragma("unroll") \
      for (int m = 0; m < 4; ++m) \
        _Pragma("unroll") \
        for (int n = 0; n < 4; ++n) \
          acc[m][n] = __builtin_amdgcn_mfma_f32_16x16x32_bf16(af[m], bv[n], acc[m][n], 0, 0, 0); \
    } \
  } while (0)

  // ---- prologue: A(k0)->regs->At, B(k0)->Bt[0] (left in flight) ----
  LOADA(k0);
  STAGEB(0, k0);
  CVTWRITEA;                 // compiler auto-waits vmcnt(4) for a0..a7
  LG0; SCHED0;               // my ds_writes done before first barrier

  int buf = 0;
#pragma unroll 1
  for (int kt = k0; kt < kend; kt += 64) {
    bool more = (kt + 64) < kend;
    if (more) {
      LOADA(kt + 64);        // 8 SSA loads in flight
      STAGEB(buf ^ 1, kt + 64);  // 4 lds-loads in flight
      VM12; SCHED0;          // retire only PREV iter's B4 (this iter's 12 stay out)
    } else {
      VM0; SCHED0;           // last iter: drain the final B4
    }
    SBAR; SCHED0;            // publish: At(kt) + Bt[buf] ready everywhere
    MFMAPHASE(buf);
    SBAR;                    // all At readers done -> safe to overwrite
    if (more) {
      CVTWRITEA;             // auto vmcnt(4) for a-regs; swizzled ds_write
      LG0; SCHED0;           // writes drained before next iter's barrier
    }
    buf ^= 1;
  }

#undef LOADA
#undef CVTWRITEA
#undef STAGEB
#undef MFMAPHASE

#pragma unroll
  for (int m = 0; m < 4; ++m)
#pragma unroll
    for (int n = 0; n < 4; ++n)
#pragma unroll
      for (int r = 0; r < 4; ++r) {
        int row = rowBase + wr * 64 + m * 16 + fq * 4 + r;
        int col = colBase + wc * 64 + n * 16 + fr;
        Pd[(size_t)row * 512 + col] = f2bf(acc[m][n][r]);
      }
}

// ---------------- reduce split-K bf16 partials -> bf16 Q/K/V ----------------
__global__ __launch_bounds__(256) void reduce_qkv(
    const ushort* __restrict__ part, ushort* __restrict__ Qp, ushort* __restrict__ Kp,
    ushort* __restrict__ Vp, int lgs)
{
  int g = blockIdx.y;
  ushort* dst = g == 0 ? Qp : (g == 1 ? Kp : Vp);
  const ushort* p = part + (((size_t)g) << lgs) * 1048576;
  int i = (blockIdx.x * 256 + threadIdx.x) * 8;
  int splits = 1 << lgs;
  float accv[8];
  {
    bf16x8 v = *(const bf16x8*)(p + i);
#pragma unroll
    for (int j = 0; j < 8; ++j) accv[j] = bf2f((ushort)v[j]);
  }
  for (int s = 1; s < splits; ++s) {
    bf16x8 v = *(const bf16x8*)(p + (size_t)s * 1048576 + i);
#pragma unroll
    for (int j = 0; j < 8; ++j) accv[j] += bf2f((ushort)v[j]);
  }
  ushort u[8];
#pragma unroll
  for (int j = 0; j < 8; ++j) u[j] = f2bf(accv[j]);
  *(uint4*)(dst + i) = *(uint4*)u;
}

// ---------------- attention: per (b,h, row-half) block ----------------
__global__ __launch_bounds__(256) void attn(
    const ushort* __restrict__ Qp, const ushort* __restrict__ Kp, const ushort* __restrict__ Vp,
    float* __restrict__ Obuf, const float* __restrict__ temp)
{
  __shared__ __align__(16) ushort Qs[64 * 64];    // [crow][d]
  __shared__ __align__(16) ushort Ks[128 * 64];   // [e][d]
  __shared__ __align__(16) ushort Vt[64 * 128];   // [d][e] (transposed)
  __shared__ __align__(16) float  Sl[64 * 128];   // scores
  __shared__ __align__(16) ushort Pl[64 * 128];   // exp(S-max) bf16
  __shared__ float rsum[64];
  int bh = blockIdx.y, b = bh >> 3, h = bh & 7;
  int c0 = blockIdx.x * 64;
  int tid = threadIdx.x, l = tid & 63, w = tid >> 6;
  int wr = w >> 1, wc = w & 1, fr = l & 15, fq = l >> 4;
  float invT = 1.0f / temp[0];
  const size_t rowQ = (size_t)(b * 128 + c0);

  // stage Q (64 rows x 64 d)
#pragma unroll
  for (int j = 0; j < 2; ++j) {
    int c = ((w * 2 + j) << 6) + l, row = c >> 3, cc = c & 7;
    __builtin_amdgcn_global_load_lds(AS1(Qp + (rowQ + row) * 512 + h * 64 + cc * 8),
                                     AS3((char*)Qs + (w * 2 + j) * 1024), 16, 0, 0);
  }
  // stage K (128 rows x 64 d)
#pragma unroll
  for (int j = 0; j < 4; ++j) {
    int c = ((w * 4 + j) << 6) + l, row = c >> 3, cc = c & 7;
    __builtin_amdgcn_global_load_lds(AS1(Kp + (size_t)(b * 128 + row) * 512 + h * 64 + cc * 8),
                                     AS3((char*)Ks + (w * 4 + j) * 1024), 16, 0, 0);
  }
  // stage V transposed: Vt[d][e]
#pragma unroll
  for (int t = 0; t < 4; ++t) {
    int ch = tid + t * 256, e = ch >> 3, d0 = (ch & 7) * 8;
    bf16x8 vv = *(const bf16x8*)(Vp + (size_t)(b * 128 + e) * 512 + h * 64 + d0);
#pragma unroll
    for (int j = 0; j < 8; ++j) Vt[(d0 + j) * 128 + e] = (ushort)vv[j];
  }
  __syncthreads();

  // S = Q*K^T (64x128)
  f32x4 sa[2][4];
#pragma unroll
  for (int m = 0; m < 2; ++m)
#pragma unroll
    for (int n = 0; n < 4; ++n) sa[m][n] = (f32x4){0.f, 0.f, 0.f, 0.f};
#pragma unroll
  for (int kc = 0; kc < 2; ++kc) {
    bf16x8 aQ[2], bK[4];
#pragma unroll
    for (int m = 0; m < 2; ++m)
      aQ[m] = *(const bf16x8*)&Qs[(wr * 32 + m * 16 + fr) * 64 + kc * 32 + fq * 8];
#pragma unroll
    for (int n = 0; n < 4; ++n)
      bK[n] = *(const bf16x8*)&Ks[(wc * 64 + n * 16 + fr) * 64 + kc * 32 + fq * 8];
#pragma unroll
    for (int m = 0; m < 2; ++m)
#pragma unroll
      for (int n = 0; n < 4; ++n)
        sa[m][n] = __builtin_amdgcn_mfma_f32_16x16x32_bf16(aQ[m], bK[n], sa[m][n], 0, 0, 0);
  }
#pragma unroll
  for (int m = 0; m < 2; ++m)
#pragma unroll
    for (int n = 0; n < 4; ++n)
#pragma unroll
      for (int r = 0; r < 4; ++r)
        Sl[(wr * 32 + m * 16 + fq * 4 + r) * 128 + wc * 64 + n * 16 + fr] = sa[m][n][r] * invT;
  __syncthreads();

  // softmax: 4 threads per row, 32 cols each
  {
    int row = tid >> 2, qq = tid & 3;
    const float* srow = Sl + row * 128 + qq * 32;
    float4 va[8];
#pragma unroll
    for (int i = 0; i < 8; ++i) va[i] = *(const float4*)(srow + i * 4);
    float mx = -1e30f;
#pragma unroll
    for (int i = 0; i < 8; ++i)
      mx = fmaxf(mx, fmaxf(fmaxf(va[i].x, va[i].y), fmaxf(va[i].z, va[i].w)));
    mx = fmaxf(mx, __shfl_xor(mx, 1));
    mx = fmaxf(mx, __shfl_xor(mx, 2));
    float ssum = 0.f;
    ushort* prow = Pl + row * 128 + qq * 32;
#pragma unroll
    for (int i = 0; i < 8; ++i) {
      float e0 = __expf(va[i].x - mx), e1 = __expf(va[i].y - mx);
      float e2 = __expf(va[i].z - mx), e3 = __expf(va[i].w - mx);
      ssum += (e0 + e1) + (e2 + e3);
      ushort4 u; u.x = f2bf(e0); u.y = f2bf(e1); u.z = f2bf(e2); u.w = f2bf(e3);
      *(ushort4*)(prow + i * 4) = u;
    }
    ssum += __shfl_xor(ssum, 1);
    ssum += __shfl_xor(ssum, 2);
    if (qq == 0) rsum[row] = ssum;
  }
  __syncthreads();

  // O = P*V (64x64)
  f32x4 oa[2][2];
#pragma unroll
  for (int m = 0; m < 2; ++m)
#pragma unroll
    for (int n = 0; n < 2; ++n) oa[m][n] = (f32x4){0.f, 0.f, 0.f, 0.f};
#pragma unroll
  for (int kc = 0; kc < 4; ++kc) {
    bf16x8 aP[2], bV[2];
#pragma unroll
    for (int m = 0; m < 2; ++m)
      aP[m] = *(const bf16x8*)&Pl[(wr * 32 + m * 16 + fr) * 128 + kc * 32 + fq * 8];
#pragma unroll
    for (int n = 0; n < 2; ++n)
      bV[n] = *(const bf16x8*)&Vt[(wc * 32 + n * 16 + fr) * 128 + kc * 32 + fq * 8];
#pragma unroll
    for (int m = 0; m < 2; ++m)
#pragma unroll
      for (int n = 0; n < 2; ++n)
        oa[m][n] = __builtin_amdgcn_mfma_f32_16x16x32_bf16(aP[m], bV[n], oa[m][n], 0, 0, 0);
  }
#pragma unroll
  for (int m = 0; m < 2; ++m)
#pragma unroll
    for (int n = 0; n < 2; ++n)
#pragma unroll
      for (int r = 0; r < 4; ++r) {
        int row = wr * 32 + m * 16 + fq * 4 + r, col = wc * 32 + n * 16 + fr;
        Obuf[(rowQ + row) * 512 + h * 64 + col] = oa[m][n][r] / rsum[row];
      }
}

// ---------------- swish + LayerNorm over D=512 (wave per row), out bf16 ----------------
__global__ __launch_bounds__(256) void swish_ln(
    const float* __restrict__ O, ushort* __restrict__ X,
    const float* __restrict__ gamma, const float* __restrict__ beta)
{
  int row = blockIdx.x * 4 + (threadIdx.x >> 6);
  int lane = threadIdx.x & 63;
  const float* x = O + (size_t)row * 512 + lane * 8;
  float4 va = *(const float4*)(x);
  float4 vb = *(const float4*)(x + 4);
  float y[8] = {va.x, va.y, va.z, va.w, vb.x, vb.y, vb.z, vb.w};
  float s = 0.f, sq = 0.f;
#pragma unroll
  for (int i = 0; i < 8; ++i) {
    y[i] = y[i] / (1.f + __expf(-y[i]));
    s += y[i]; sq += y[i] * y[i];
  }
#pragma unroll
  for (int o = 1; o < 64; o <<= 1) { s += __shfl_xor(s, o); sq += __shfl_xor(sq, o); }
  float mean = s * (1.f / 512.f);
  float var = (sq - s * mean) * (1.f / 511.f);   // unbiased (ddof=1)
  float inv = 1.f / (sqrtf(var) + 1e-6f);
  const float4 g0 = *(const float4*)(gamma + lane * 8);
  const float4 g1 = *(const float4*)(gamma + lane * 8 + 4);
  const float4 b0 = *(const float4*)(beta + lane * 8);
  const float4 b1 = *(const float4*)(beta + lane * 8 + 4);
  float gg[8] = {g0.x, g0.y, g0.z, g0.w, g1.x, g1.y, g1.z, g1.w};
  float bb[8] = {b0.x, b0.y, b0.z, b0.w, b1.x, b1.y, b1.z, b1.w};
  ushort u[8];
#pragma unroll
  for (int i = 0; i < 8; ++i) u[i] = f2bf(gg[i] * (y[i] - mean) * inv + bb[i]);
  *(uint4*)(X + (size_t)row * 512 + lane * 8) = *(uint4*)u;
}

// ---------------- fc GEMM + residual -> bf16 valbuf + BN partial sums ----------------
__global__ __launch_bounds__(256) void gemm_fc(
    const ushort* __restrict__ A, const ushort* __restrict__ Bm,
    const float* __restrict__ resid, ushort* __restrict__ valb,
    float* __restrict__ bn_sum, float* __restrict__ bn_sq)
{
  __shared__ __align__(16) ushort At[128 * 64];
  __shared__ __align__(16) ushort Bt[128 * 64];
  __shared__ float csum[128], csq[128];
  const int K = 512;
  int rowBase = blockIdx.x * 128;   // 16
  int colBase = blockIdx.y * 128;   // 32
  int tid = threadIdx.x, l = tid & 63, w = tid >> 6;
  int wr = w >> 1, wc = w & 1, fr = l & 15, fq = l >> 4;
  if (tid < 128) { csum[tid] = 0.f; csq[tid] = 0.f; }
  f32x4 acc[4][4];
#pragma unroll
  for (int m = 0; m < 4; ++m)
#pragma unroll
    for (int n = 0; n < 4; ++n) acc[m][n] = (f32x4){0.f, 0.f, 0.f, 0.f};

  for (int kt = 0; kt < K; kt += 64) {
#pragma unroll
    for (int j = 0; j < 4; ++j) {
      int c = ((w * 4 + j) << 6) + l;
      int row = c >> 3, cc = c & 7;
      __builtin_amdgcn_global_load_lds(AS1(A + (size_t)(rowBase + row) * K + kt + cc * 8),
                                       AS3((char*)At + (w * 4 + j) * 1024), 16, 0, 0);
      __builtin_amdgcn_global_load_lds(AS1(Bm + (size_t)(colBase + row) * K + kt + cc * 8),
                                       AS3((char*)Bt + (w * 4 + j) * 1024), 16, 0, 0);
    }
    __syncthreads();
#pragma unroll
    for (int kc = 0; kc < 2; ++kc) {
      bf16x8 af[4], bfv[4];
#pragma unroll
      for (int m = 0; m < 4; ++m)
        af[m] = *(const bf16x8*)&At[(wr * 64 + m * 16 + fr) * 64 + kc * 32 + fq * 8];
#pragma unroll
      for (int n = 0; n < 4; ++n)
        bfv[n] = *(const bf16x8*)&Bt[(wc * 64 + n * 16 + fr) * 64 + kc * 32 + fq * 8];
#pragma unroll
      for (int m = 0; m < 4; ++m)
#pragma unroll
        for (int n = 0; n < 4; ++n)
          acc[m][n] = __builtin_amdgcn_mfma_f32_16x16x32_bf16(af[m], bfv[n], acc[m][n], 0, 0, 0);
    }
    __syncthreads();
  }
  // epilogue: val = acc + residual -> bf16 valbuf; per-channel sums (fp32) for BN
#pragma unroll
  for (int m = 0; m < 4; ++m)
#pragma unroll
    for (int r = 0; r < 4; ++r) {
      float ps = 0.f, pq = 0.f;
#pragma unroll
      for (int n = 0; n < 4; ++n) {
        int row = rowBase + wr * 64 + m * 16 + fq * 4 + r;
        int col = colBase + wc * 64 + n * 16 + fr;
        size_t idx = (size_t)row * 4096 + col;
        float val = acc[m][n][r] + resid[idx];
        valb[idx] = f2bf(val);
        ps += val; pq += val * val;
      }
#pragma unroll
      for (int o = 1; o < 16; o <<= 1) { ps += __shfl_xor(ps, o); pq += __shfl_xor(pq, o); }
      if (fr == 0) {
        int ch = wr * 64 + m * 16 + fq * 4 + r;   // rowBase % 128 == 0
        atomicAdd(&csum[ch], ps);
        atomicAdd(&csq[ch], pq);
      }
    }
  __syncthreads();
  if (tid < 128) {
    atomicAdd(&bn_sum[tid], csum[tid]);
    atomicAdd(&bn_sq[tid], csq[tid]);
  }
}

// ---------------- BatchNorm finalize: bf16 valbuf -> fp32 d_out ----------------
__global__ __launch_bounds__(256) void bn_norm(
    const ushort* __restrict__ valb, float* __restrict__ out,
    const float* __restrict__ bn_sum, const float* __restrict__ bn_sq,
    const float* __restrict__ gamma, const float* __restrict__ beta)
{
  __shared__ float sc[128], sh[128];
  const float inv_n = 1.f / 65536.f;
  int tid = threadIdx.x;
  if (tid < 128) {
    float mean = bn_sum[tid] * inv_n;
    float var = bn_sq[tid] * inv_n - mean * mean;
    float g = gamma[tid] * rsqrtf(var + 1e-5f);
    sc[tid] = g;
    sh[tid] = beta[tid] - mean * g;
  }
  __syncthreads();
  int stride = gridDim.x * blockDim.x;
  for (int v = blockIdx.x * blockDim.x + tid; v < 1048576; v += stride) {
    int elem = v * 8;
    int ch = (elem >> 12) & 127;
    float g = sc[ch], bta = sh[ch];
    bf16x8 x = *(const bf16x8*)(valb + elem);
    float4 o0, o1;
    o0.x = bf2f((ushort)x[0]) * g + bta;
    o0.y = bf2f((ushort)x[1]) * g + bta;
    o0.z = bf2f((ushort)x[2]) * g + bta;
    o0.w = bf2f((ushort)x[3]) * g + bta;
    o1.x = bf2f((ushort)x[4]) * g + bta;
    o1.y = bf2f((ushort)x[5]) * g + bta;
    o1.z = bf2f((ushort)x[6]) * g + bta;
    o1.w = bf2f((ushort)x[7]) * g + bta;
    *(float4*)(out + elem) = o0;
    *(float4*)(out + elem + 4) = o1;
  }
}

extern "C" void kernel_launch(void* const* d_in, const int* in_sizes, int n_in,
                              void* d_out, int out_size, void* d_ws, size_t ws_size,
                              hipStream_t stream)
{
  const float* v_in = (const float*)d_in[0];
  const float* k_in = (const float*)d_in[1];
  const float* q_in = (const float*)d_in[2];
  const float* w_qs = (const float*)d_in[3];
  const float* w_ks = (const float*)d_in[4];
  const float* w_vs = (const float*)d_in[5];
  const float* w_fc = (const float*)d_in[6];
  const float* ln_g = (const float*)d_in[7];
  const float* ln_b = (const float*)d_in[8];
  const float* temp = (const float*)d_in[9];
  const float* bn_g = (const float*)d_in[10];
  const float* bn_b = (const float*)d_in[11];
  float* out = (float*)d_out;

  char* ws = (char*)d_ws;
  size_t off = 0;
  auto alloc = [&](size_t bytes) { char* p = ws + off; off += bytes; return p; };
  ushort* wq  = (ushort*)alloc(512ull * 4096 * 2);
  ushort* wk  = (ushort*)alloc(512ull * 4096 * 2);
  ushort* wv  = (ushort*)alloc(512ull * 4096 * 2);
  ushort* wfc = (ushort*)alloc(512ull * 4096 * 2);
  ushort* Qp  = (ushort*)alloc(2048ull * 512 * 2);
  ushort* Kp  = (ushort*)alloc(2048ull * 512 * 2);
  ushort* Vp  = (ushort*)alloc(2048ull * 512 * 2);
  float*  Obuf= (float*)alloc(2048ull * 512 * 4);
  ushort* X16 = (ushort*)alloc(2048ull * 512 * 2);
  ushort* valb= (ushort*)alloc(2048ull * 4096 * 2);
  float*  bns = (float*)alloc(128 * 4);
  float*  bnq = (float*)alloc(128 * 4);

  // split-K partial planes: 3*(1<<lgs) planes of 2048*512 bf16
  int lgs = 2;                       // 4-way split-K -> 768 blocks (~3 blocks/CU)
  if (off + (3ull << lgs) * 1048576 * 2 > ws_size) lgs = 1;
  if (off + (3ull << lgs) * 1048576 * 2 > ws_size) lgs = 0;
  ushort* part = (ushort*)alloc((3ull << lgs) * 1048576 * 2);

  hipMemsetAsync(bns, 0, 256 * 4, stream);   // zero bns+bnq (adjacent)

  pack4<<<dim3(512, 4), 256, 0, stream>>>(w_qs, w_ks, w_vs, w_fc, wq, wk, wv, wfc,
                                          512 * 4096);
  gemm_qkv<<<16 * 4 * (3 << lgs), 256, 0, stream>>>(q_in, k_in, v_in, wq, wk, wv, part, lgs);
  reduce_qkv<<<dim3(512, 3), 256, 0, stream>>>(part, Qp, Kp, Vp, lgs);
  attn<<<dim3(2, 128), 256, 0, stream>>>(Qp, Kp, Vp, Obuf, temp);
  swish_ln<<<512, 256, 0, stream>>>(Obuf, X16, ln_g, ln_b);
  gemm_fc<<<dim3(16, 32), 256, 0, stream>>>(X16, wfc, v_in, valb, bns, bnq);
  bn_norm<<<2048, 256, 0, stream>>>(valb, out, bns, bnq, bn_g, bn_b);
}